// Round 1
// baseline (184.417 us; speedup 1.0000x reference)
//
#include <hip/hip_runtime.h>

#define NN 4096
#define DD 128
#define MARGIN_F 0.3f

// ws layout (4-byte units):
//   [0      .. N)    a2[i]   = ||p1_i||^2
//   [N      .. 2N)   b2[j]   = ||p2_j||^2
//   [2N     .. 3N)   c[i]    = dist_ap_i - a2_i + margin
//   [3N     .. 4N)   rowmax[i] (uint bits of nonneg float)
//   [4N]             sum accumulator (float)

__global__ __launch_bounds__(256) void ptl_row_stats(
    const float* __restrict__ p1, const float* __restrict__ p2,
    float* __restrict__ a2, float* __restrict__ b2, float* __restrict__ c) {
  int row = blockIdx.x * 4 + (threadIdx.x >> 6);
  int lane = threadIdx.x & 63;
  float2 x = ((const float2*)(p1 + (size_t)row * DD))[lane];
  float2 y = ((const float2*)(p2 + (size_t)row * DD))[lane];
  float sa = x.x * x.x + x.y * x.y;
  float sb = y.x * y.x + y.y * y.y;
  float d0 = x.x - y.x, d1 = x.y - y.y;
  float sd = d0 * d0 + d1 * d1;
#pragma unroll
  for (int off = 32; off > 0; off >>= 1) {
    sa += __shfl_down(sa, off);
    sb += __shfl_down(sb, off);
    sd += __shfl_down(sd, off);
  }
  if (lane == 0) {
    a2[row] = sa;
    b2[row] = sb;
    c[row] = sd - sa + MARGIN_F;  // dist_ap - a2 + margin
  }
}

__global__ __launch_bounds__(256) void ptl_pair_tile(
    const float* __restrict__ p1, const float* __restrict__ p2,
    const float* __restrict__ a2, const float* __restrict__ b2,
    const float* __restrict__ c, unsigned int* __restrict__ rowmax,
    float* __restrict__ sumacc) {
  __shared__ float As[8][64];
  __shared__ float Bs1[8][64];
  __shared__ float Bs2[8][64];

  const int tx = threadIdx.x & 15;   // j sub-tile (0..15)
  const int ty = threadIdx.x >> 4;   // i sub-tile (0..15)
  const int iBase = blockIdx.y * 64;
  const int jBase = blockIdx.x * 64;

  float acc1[4][4] = {{0.f}};
  float acc2[4][4] = {{0.f}};

  const int lrow = threadIdx.x >> 2;       // 0..63
  const int lk = (threadIdx.x & 3) * 2;    // 0,2,4,6

  for (int kk = 0; kk < DD; kk += 8) {
    float2 av  = *(const float2*)(p1 + (size_t)(iBase + lrow) * DD + kk + lk);
    float2 b1v = *(const float2*)(p1 + (size_t)(jBase + lrow) * DD + kk + lk);
    float2 b2v = *(const float2*)(p2 + (size_t)(jBase + lrow) * DD + kk + lk);
    __syncthreads();
    As[lk][lrow] = av.x;   As[lk + 1][lrow] = av.y;
    Bs1[lk][lrow] = b1v.x; Bs1[lk + 1][lrow] = b1v.y;
    Bs2[lk][lrow] = b2v.x; Bs2[lk + 1][lrow] = b2v.y;
    __syncthreads();
#pragma unroll
    for (int k = 0; k < 8; ++k) {
      float a[4], u1[4], u2[4];
#pragma unroll
      for (int u = 0; u < 4; ++u) a[u] = As[k][ty * 4 + u];
#pragma unroll
      for (int v = 0; v < 4; ++v) { u1[v] = Bs1[k][tx * 4 + v]; u2[v] = Bs2[k][tx * 4 + v]; }
#pragma unroll
      for (int u = 0; u < 4; ++u)
#pragma unroll
        for (int v = 0; v < 4; ++v) {
          acc1[u][v] = fmaf(a[u], u1[v], acc1[u][v]);
          acc2[u][v] = fmaf(a[u], u2[v], acc2[u][v]);
        }
    }
  }

  // Epilogue: v = c_i - n2_j + 2*s ; relu ; zero diagonal ; row-max + sum
  float ci[4], a2j[4], b2j[4];
#pragma unroll
  for (int u = 0; u < 4; ++u) ci[u] = c[iBase + ty * 4 + u];
#pragma unroll
  for (int v = 0; v < 4; ++v) {
    a2j[v] = a2[jBase + tx * 4 + v];
    b2j[v] = b2[jBase + tx * 4 + v];
  }

  float lsum = 0.f;
  float rmax[4] = {0.f, 0.f, 0.f, 0.f};
#pragma unroll
  for (int u = 0; u < 4; ++u) {
    const int gi = iBase + ty * 4 + u;
#pragma unroll
    for (int v = 0; v < 4; ++v) {
      const int gj = jBase + tx * 4 + v;
      float v1 = fmaxf(ci[u] - a2j[v] + 2.f * acc1[u][v], 0.f);
      float v2 = fmaxf(ci[u] - b2j[v] + 2.f * acc2[u][v], 0.f);
      if (gi == gj) { v1 = 0.f; v2 = 0.f; }
      lsum += v1 + v2;
      rmax[u] = fmaxf(rmax[u], fmaxf(v1, v2));
    }
  }

  // max across the 16 tx lanes sharing a row group (lanes [g*16, g*16+15])
#pragma unroll
  for (int off = 8; off > 0; off >>= 1) {
#pragma unroll
    for (int u = 0; u < 4; ++u)
      rmax[u] = fmaxf(rmax[u], __shfl_down(rmax[u], off));
  }
  if (tx == 0) {
#pragma unroll
    for (int u = 0; u < 4; ++u)
      atomicMax(&rowmax[iBase + ty * 4 + u], __float_as_uint(rmax[u]));
  }

  // block sum -> one atomicAdd
#pragma unroll
  for (int off = 32; off > 0; off >>= 1) lsum += __shfl_down(lsum, off);
  __shared__ float wsum[4];
  if ((threadIdx.x & 63) == 0) wsum[threadIdx.x >> 6] = lsum;
  __syncthreads();
  if (threadIdx.x == 0)
    atomicAdd(sumacc, wsum[0] + wsum[1] + wsum[2] + wsum[3]);
}

__global__ __launch_bounds__(256) void ptl_finalize(
    const unsigned int* __restrict__ rowmax, const float* __restrict__ sumacc,
    float* __restrict__ out) {
  float s = 0.f;
  for (int i = threadIdx.x; i < NN; i += 256)
    s += __uint_as_float(rowmax[i]);
#pragma unroll
  for (int off = 32; off > 0; off >>= 1) s += __shfl_down(s, off);
  __shared__ float ws[4];
  if ((threadIdx.x & 63) == 0) ws[threadIdx.x >> 6] = s;
  __syncthreads();
  if (threadIdx.x == 0) {
    out[0] = (ws[0] + ws[1] + ws[2] + ws[3]) / (float)NN;
    out[1] = sumacc[0] / (2.0f * (float)NN * (float)(NN - 1));
  }
}

extern "C" void kernel_launch(void* const* d_in, const int* in_sizes, int n_in,
                              void* d_out, int out_size, void* d_ws, size_t ws_size,
                              hipStream_t stream) {
  const float* p1 = (const float*)d_in[0];
  const float* p2 = (const float*)d_in[1];
  float* a2 = (float*)d_ws;
  float* b2 = a2 + NN;
  float* c  = b2 + NN;
  unsigned int* rowmax = (unsigned int*)(c + NN);
  float* sumacc = (float*)(rowmax + NN);

  // zero rowmax + sum accumulator (ws is poisoned 0xAA before every launch)
  hipMemsetAsync(rowmax, 0, (NN + 1) * sizeof(float), stream);

  ptl_row_stats<<<NN / 4, 256, 0, stream>>>(p1, p2, a2, b2, c);

  dim3 grid(NN / 64, NN / 64);
  ptl_pair_tile<<<grid, 256, 0, stream>>>(p1, p2, a2, b2, c, rowmax, sumacc);

  ptl_finalize<<<1, 256, 0, stream>>>(rowmax, sumacc, (float*)d_out);
}

// Round 2
// 125.816 us; speedup vs baseline: 1.4658x; 1.4658x over previous
//
#include <hip/hip_runtime.h>
#include <hip/hip_bf16.h>

#define NN 4096
#define DD 128
#define MARGIN_F 0.3f
#define JC 256          // columns swept per block
#define NBLK ((NN / JC) * (NN / 64))   // 16 * 64 = 1024 mfma blocks

typedef __attribute__((ext_vector_type(8))) short bf16x8;   // 8 bf16 = 4 VGPRs
typedef __attribute__((ext_vector_type(4))) float f32x4;

// ws layout:
//   [0 .. 1MB)        p1b  (4096*128 bf16)
//   [1MB .. 2MB)      p2b
//   then fp32 arrays: a2[N], b2[N], c[N], rowmax[N] (uint), blksum[NBLK]

__device__ __forceinline__ ushort f2bf(float f) {
  __hip_bfloat16 h = __float2bfloat16(f);   // RNE
  return *reinterpret_cast<ushort*>(&h);
}

// Fused: bf16 conversion + row stats (a2, b2, c) — one wave per row.
__global__ __launch_bounds__(256) void ptl_prep(
    const float* __restrict__ p1, const float* __restrict__ p2,
    ushort* __restrict__ p1b, ushort* __restrict__ p2b,
    float* __restrict__ a2, float* __restrict__ b2, float* __restrict__ c) {
  int row = blockIdx.x * 4 + (threadIdx.x >> 6);
  int lane = threadIdx.x & 63;
  float2 x = ((const float2*)(p1 + (size_t)row * DD))[lane];
  float2 y = ((const float2*)(p2 + (size_t)row * DD))[lane];
  ushort2 xb, yb;
  xb.x = f2bf(x.x); xb.y = f2bf(x.y);
  yb.x = f2bf(y.x); yb.y = f2bf(y.y);
  ((ushort2*)(p1b + (size_t)row * DD))[lane] = xb;
  ((ushort2*)(p2b + (size_t)row * DD))[lane] = yb;
  float sa = x.x * x.x + x.y * x.y;
  float sb = y.x * y.x + y.y * y.y;
  float d0 = x.x - y.x, d1 = x.y - y.y;
  float sd = d0 * d0 + d1 * d1;
#pragma unroll
  for (int off = 32; off > 0; off >>= 1) {
    sa += __shfl_down(sa, off);
    sb += __shfl_down(sb, off);
    sd += __shfl_down(sd, off);
  }
  if (lane == 0) {
    a2[row] = sa;
    b2[row] = sb;
    c[row] = sd - sa + MARGIN_F;  // dist_ap - ||p1_i||^2 + margin
  }
}

// LDS-free MFMA sweep. Wave w of block (bx,by): rows by*64+w*16 .. +15,
// cols bx*JC .. +JC-1. A/B frags: row-major gather row*128 + quad*8 (NT GEMM).
// C layout: col = lane&15, row = quad*4 + reg  [verified m89].
__global__ __launch_bounds__(256) void ptl_mfma(
    const ushort* __restrict__ p1b, const ushort* __restrict__ p2b,
    const float* __restrict__ a2, const float* __restrict__ b2,
    const float* __restrict__ c, unsigned int* __restrict__ rowmax,
    float* __restrict__ blksum) {
  const int tid = threadIdx.x;
  const int w = tid >> 6;
  const int lane = tid & 63;
  const int col16 = lane & 15;
  const int quad = lane >> 4;
  const int rowBase = blockIdx.y * 64 + w * 16;
  const int jBase = blockIdx.x * JC;

  // A fragments for all K=128 (k = s*32 + quad*8 + j)
  bf16x8 afr[4];
  {
    const ushort* pa = p1b + (size_t)(rowBase + col16) * DD + quad * 8;
#pragma unroll
    for (int s = 0; s < 4; ++s) afr[s] = *(const bf16x8*)(pa + s * 32);
  }

  float cv[4];
#pragma unroll
  for (int r = 0; r < 4; ++r) cv[r] = c[rowBase + quad * 4 + r];

  float rmax[4] = {0.f, 0.f, 0.f, 0.f};
  float lsum = 0.f;

  for (int jt = 0; jt < JC / 16; ++jt) {
    const int jcol = jBase + jt * 16 + col16;
    const ushort* pb1 = p1b + (size_t)jcol * DD + quad * 8;
    const ushort* pb2 = p2b + (size_t)jcol * DD + quad * 8;
    f32x4 s1 = {0.f, 0.f, 0.f, 0.f};
    f32x4 s2 = {0.f, 0.f, 0.f, 0.f};
#pragma unroll
    for (int s = 0; s < 4; ++s) {
      bf16x8 b1 = *(const bf16x8*)(pb1 + s * 32);
      bf16x8 b2f = *(const bf16x8*)(pb2 + s * 32);
      s1 = __builtin_amdgcn_mfma_f32_16x16x32_bf16(afr[s], b1, s1, 0, 0, 0);
      s2 = __builtin_amdgcn_mfma_f32_16x16x32_bf16(afr[s], b2f, s2, 0, 0, 0);
    }
    const float aj = a2[jcol];
    const float bj = b2[jcol];
    if ((jBase + jt * 16) == rowBase) {  // diagonal tile (wave-uniform branch)
#pragma unroll
      for (int r = 0; r < 4; ++r) {
        float v1 = fmaxf(fmaf(2.f, s1[r], cv[r] - aj), 0.f);
        float v2 = fmaxf(fmaf(2.f, s2[r], cv[r] - bj), 0.f);
        if (col16 == quad * 4 + r) { v1 = 0.f; v2 = 0.f; }
        lsum += v1 + v2;
        rmax[r] = fmaxf(rmax[r], fmaxf(v1, v2));
      }
    } else {
#pragma unroll
      for (int r = 0; r < 4; ++r) {
        float v1 = fmaxf(fmaf(2.f, s1[r], cv[r] - aj), 0.f);
        float v2 = fmaxf(fmaf(2.f, s2[r], cv[r] - bj), 0.f);
        lsum += v1 + v2;
        rmax[r] = fmaxf(rmax[r], fmaxf(v1, v2));
      }
    }
  }

  // row-max across the 16 col lanes of each quad (xor<16 stays in-quad)
#pragma unroll
  for (int off = 8; off > 0; off >>= 1)
#pragma unroll
    for (int r = 0; r < 4; ++r)
      rmax[r] = fmaxf(rmax[r], __shfl_xor(rmax[r], off));
  if (col16 == 0) {
#pragma unroll
    for (int r = 0; r < 4; ++r)
      atomicMax(&rowmax[rowBase + quad * 4 + r], __float_as_uint(rmax[r]));
  }

  // block partial sum -> blksum[bid] (no atomics)
#pragma unroll
  for (int off = 32; off > 0; off >>= 1) lsum += __shfl_down(lsum, off);
  __shared__ float wsum[4];
  if (lane == 0) wsum[w] = lsum;
  __syncthreads();
  if (tid == 0)
    blksum[blockIdx.y * gridDim.x + blockIdx.x] =
        wsum[0] + wsum[1] + wsum[2] + wsum[3];
}

__global__ __launch_bounds__(256) void ptl_finalize(
    const unsigned int* __restrict__ rowmax, const float* __restrict__ blksum,
    float* __restrict__ out) {
  float sm = 0.f, ss = 0.f;
  for (int i = threadIdx.x; i < NN; i += 256) sm += __uint_as_float(rowmax[i]);
  for (int i = threadIdx.x; i < NBLK; i += 256) ss += blksum[i];
#pragma unroll
  for (int off = 32; off > 0; off >>= 1) {
    sm += __shfl_down(sm, off);
    ss += __shfl_down(ss, off);
  }
  __shared__ float wm[4], wsv[4];
  if ((threadIdx.x & 63) == 0) {
    wm[threadIdx.x >> 6] = sm;
    wsv[threadIdx.x >> 6] = ss;
  }
  __syncthreads();
  if (threadIdx.x == 0) {
    out[0] = (wm[0] + wm[1] + wm[2] + wm[3]) / (float)NN;
    out[1] = (wsv[0] + wsv[1] + wsv[2] + wsv[3]) /
             (2.0f * (float)NN * (float)(NN - 1));
  }
}

extern "C" void kernel_launch(void* const* d_in, const int* in_sizes, int n_in,
                              void* d_out, int out_size, void* d_ws, size_t ws_size,
                              hipStream_t stream) {
  const float* p1 = (const float*)d_in[0];
  const float* p2 = (const float*)d_in[1];
  ushort* p1b = (ushort*)d_ws;
  ushort* p2b = p1b + (size_t)NN * DD;
  float* a2 = (float*)(p2b + (size_t)NN * DD);
  float* b2 = a2 + NN;
  float* c = b2 + NN;
  unsigned int* rowmax = (unsigned int*)(c + NN);
  float* blksum = (float*)(rowmax + NN);

  // rowmax must start at 0 (uint-compare of nonneg floats); ws is 0xAA-poisoned
  hipMemsetAsync(rowmax, 0, NN * sizeof(unsigned int), stream);

  ptl_prep<<<NN / 4, 256, 0, stream>>>(p1, p2, p1b, p2b, a2, b2, c);

  dim3 grid(NN / JC, NN / 64);  // (16, 64)
  ptl_mfma<<<grid, 256, 0, stream>>>(p1b, p2b, a2, b2, c, rowmax, blksum);

  ptl_finalize<<<1, 256, 0, stream>>>(rowmax, blksum, (float*)d_out);
}